// Round 11
// baseline (248.347 us; speedup 1.0000x reference)
//
#include <hip/hip_runtime.h>

typedef unsigned short u16;
typedef unsigned int   u32;

typedef short bf16x8 __attribute__((ext_vector_type(8)));
typedef float f32x4  __attribute__((ext_vector_type(4)));

__device__ __forceinline__ float bf2f(u16 u) { return __uint_as_float(((u32)u) << 16); }
__device__ __forceinline__ u16 f2bf(float f) {
    u32 u = __float_as_uint(f);
    return (u16)((u + 0x7fffu + ((u >> 16) & 1u)) >> 16);
}

#define MFMA16(a, b, c) __builtin_amdgcn_mfma_f32_16x16x32_bf16(a, b, c, 0, 0, 0)

// ---------------------------------------------------------------------------
// K0: transpose x[b][ci][p] fp32 -> xT[b][p][ci] bf16.
// ---------------------------------------------------------------------------
__global__ __launch_bounds__(256, 4) void k_xpose(const float* __restrict__ x,
                                                  u16* __restrict__ xT) {
    __shared__ u16 Xs[128 * 128];
    const int ptile = blockIdx.x, b = blockIdx.y;
    const int t = threadIdx.x;
    const float* xb = x + (((size_t)b) << 21) + ptile * 128;
#pragma unroll
    for (int i = 0; i < 16; ++i) {
        int idx = i * 256 + t;
        int ci = idx >> 5, pq = idx & 31;
        float4 v = *(const float4*)(xb + (((size_t)ci) << 14) + pq * 4);
        u32 lo = (u32)f2bf(v.x) | ((u32)f2bf(v.y) << 16);
        u32 hi = (u32)f2bf(v.z) | ((u32)f2bf(v.w) << 16);
        uint2 pk; pk.x = lo; pk.y = hi;
        int cq = ci >> 3;
        *(uint2*)(&Xs[ci * 128 + ((pq ^ cq) << 2)]) = pk;
    }
    __syncthreads();
    u16* ob = xT + (((size_t)b) << 21) + ((size_t)(ptile * 128)) * 128;
#pragma unroll
    for (int j = 0; j < 8; ++j) {
        int p = j * 16 + (t >> 4), cq = t & 15;
        u16 tmp[8];
#pragma unroll
        for (int c = 0; c < 8; ++c) {
            int ci = cq * 8 + c;
            tmp[c] = Xs[ci * 128 + (((p >> 2) ^ cq) << 2) + (p & 3)];
        }
        *(uint4*)(&ob[(size_t)p * 128 + cq * 8]) = *(const uint4*)tmp;
    }
}

// ---------------------------------------------------------------------------
// K1 v6: qkv 1x1 conv, single launch; per-cg output layout.
//   cg 0,1 (q,k): plane written column-major  [ch][w][h]
//   cg 2   (v)  : plane written row-major     [ch][h][w]
//   Cs epilogue staging ALIASES Bt (dead after MFMA; +1 barrier) ->
//   LDS 49 -> 32 KB -> 4 blocks/CU (32 waves = occupancy cap).
// ---------------------------------------------------------------------------
__global__ __launch_bounds__(512, 6) void k_qkv(const u16* __restrict__ xT,
                                                const float* __restrict__ w,
                                                const float* __restrict__ bias,
                                                u16* __restrict__ out1) {
    extern __shared__ char smem[];
    u16* Bt = (u16*)smem;            // 32 KB swizzled [p][g]
    u16* Cs = (u16*)smem;            // [64 co][136 p] = 17 KB, ALIASES Bt
    const int h = blockIdx.x, cg = blockIdx.y, b = blockIdx.z;
    const int t = threadIdx.x;
    const int psh = (cg < 2) ? 14 : 7;       // CM : RM spatial stride shift
    const int hsh = (cg < 2) ? 7 : 14;

    const u16* xb = xT + (((size_t)b) << 21) + (h << hsh);
#pragma unroll
    for (int i = 0; i < 4; ++i) {
        int slot = i * 512 + t;
        int p = slot >> 4, g = slot & 15;
        int gg = g ^ (p & 15);
        uint4 v = *(const uint4*)(&xb[(p << psh) + gg * 8]);
        *(uint4*)(&Bt[slot * 8]) = v;
    }

    const int wave = t >> 6, lane = t & 63, m16 = lane & 15, quad = lane >> 4;
    bf16x8 afr[4];
    {
        const float* wp0 = w + (size_t)(cg * 128 + wave * 16 + m16) * 128 + quad * 8;
#pragma unroll
        for (int kk = 0; kk < 4; ++kk) {
            float4 w0 = *(const float4*)(wp0 + kk * 32);
            float4 w1 = *(const float4*)(wp0 + kk * 32 + 4);
            bf16x8 a;
            a[0] = (short)f2bf(w0.x); a[1] = (short)f2bf(w0.y);
            a[2] = (short)f2bf(w0.z); a[3] = (short)f2bf(w0.w);
            a[4] = (short)f2bf(w1.x); a[5] = (short)f2bf(w1.y);
            a[6] = (short)f2bf(w1.z); a[7] = (short)f2bf(w1.w);
            afr[kk] = a;
        }
    }
    __syncthreads();

    f32x4 acc[8] = {};
#pragma unroll
    for (int kk = 0; kk < 4; ++kk) {
        const int g = kk * 4 + quad;
#pragma unroll
        for (int nt = 0; nt < 8; ++nt) {
            int p = nt * 16 + m16;
            bf16x8 bf = *(const bf16x8*)(&Bt[p * 128 + ((g ^ (p & 15)) << 3)]);
            acc[nt] = MFMA16(afr[kk], bf, acc[nt]);
        }
    }

    float bv[4];
#pragma unroll
    for (int r = 0; r < 4; ++r) bv[r] = bias[cg * 128 + wave * 16 + quad * 4 + r];

    u16* ob = out1 + (((size_t)(b * 384 + cg * 128)) << 14) + (h << 7);

    __syncthreads();   // all Bt reads done; Cs (alias) writable

    // --- half 0: waves 0..3 stage co 0..63 ---
    if (wave < 4) {
#pragma unroll
        for (int nt = 0; nt < 8; ++nt) {
            int p = nt * 16 + m16;
#pragma unroll
            for (int r = 0; r < 4; ++r)
                Cs[(wave * 16 + quad * 4 + r) * 136 + p] = f2bf(acc[nt][r] + bv[r]);
        }
    }
    __syncthreads();
#pragma unroll
    for (int it = 0; it < 2; ++it) {
        int idx = it * 512 + t;
        int co = idx >> 4, cp = idx & 15;
        *(uint4*)(&ob[((size_t)co << 14) + cp * 8]) = *(const uint4*)(&Cs[co * 136 + cp * 8]);
    }
    __syncthreads();

    // --- half 1: waves 4..7 stage co 64..127 ---
    if (wave >= 4) {
#pragma unroll
        for (int nt = 0; nt < 8; ++nt) {
            int p = nt * 16 + m16;
#pragma unroll
            for (int r = 0; r < 4; ++r)
                Cs[((wave - 4) * 16 + quad * 4 + r) * 136 + p] = f2bf(acc[nt][r] + bv[r]);
        }
    }
    __syncthreads();
    u16* ob2 = ob + ((size_t)64 << 14);
#pragma unroll
    for (int it = 0; it < 2; ++it) {
        int idx = it * 512 + t;
        int co = idx >> 4, cp = idx & 15;
        *(uint4*)(&ob2[((size_t)co << 14) + cp * 8]) = *(const uint4*)(&Cs[co * 136 + cp * 8]);
    }
}

// ---------------------------------------------------------------------------
// K3 v11 (round-10 verbatim): fused dw3x3 + attention; dual-buffer + stageQ
// hidden under convK.  74.2 KB LDS, 2 blocks/CU, (512,4), VGPR 64, no spill.
// ---------------------------------------------------------------------------
__global__ __launch_bounds__(512, 4) void k_attn(const u16* __restrict__ qkv,
                                                 const float* __restrict__ dww,
                                                 const float* __restrict__ dwb,
                                                 const float* __restrict__ temp,
                                                 u16* __restrict__ outp) {
    extern __shared__ char smem[];
    u16* A  = (u16*)smem;                  // [128][144] raw plane (V, then Q)
    u16* Bq = (u16*)(smem + 36864);        // [128][144] raw K plane
    float* rqk = (float*)(smem + 73728);   // [128] q norms
    u16* Qt  = Bq;                         // swizzled [j][i], over K raw
    u16* Pt  = Bq;
    u16* Osh = A;

    const int ch = blockIdx.x, b = blockIdx.y;
    const int head = ch >> 5;
    const int t = threadIdx.x;
    const size_t qoff = ((size_t)(b * 384 + ch)) << 14;
    const size_t koff = qoff + ((size_t)128 << 14);
    const size_t voff = qoff + ((size_t)256 << 14);

    const int wave = t >> 6, lane = t & 63, m16 = lane & 15, quad = lane >> 4;
    const int wr = wave * 16 + m16;        // this lane's owned row

    // ---- stage V->A and K->B together (+ zero pads for both) ----
#pragma unroll
    for (int i = 0; i < 4; ++i) {
        int idx = i * 512 + t;
        int r = idx >> 4, c16 = idx & 15;
        *(uint4*)(&A[r * 144 + 8 + c16 * 8]) =
            *(const uint4*)(&qkv[voff + ((size_t)r << 7) + c16 * 8]);
        *(uint4*)(&Bq[r * 144 + 8 + c16 * 8]) =
            *(const uint4*)(&qkv[koff + ((size_t)r << 7) + c16 * 8]);
    }
    {
        uint4 z = {0, 0, 0, 0};
        if (t < 256) {
            int r = t >> 1, side = t & 1;
            *(uint4*)(&A[r * 144 + side * 136]) = z;
        } else {
            int u = t - 256;
            int r = u >> 1, side = u & 1;
            *(uint4*)(&Bq[r * 144 + side * 136]) = z;
        }
    }
    __syncthreads();

    // ---- V conv -> vfr (row-major taps; reads A) ----
    bf16x8 vfr[4];
    {
        float w9[9];
        const float* wp = dww + (size_t)(256 + ch) * 9;
#pragma unroll
        for (int i = 0; i < 9; ++i) w9[i] = wp[i];
        const float gb = dwb[256 + ch];
#pragma unroll
        for (int kk = 0; kk < 4; ++kk) {
            const int c0 = quad * 8 + kk * 32;
            float acc[8];
#pragma unroll
            for (int c = 0; c < 8; ++c) acc[c] = gb;
#pragma unroll
            for (int dy = 0; dy < 3; ++dy) {
                int rr = wr + dy - 1;
                if ((unsigned)rr < 128u) {
                    const u16* row = &A[rr * 144 + 8 + c0];
                    float v0 = bf2f(row[-1]);
                    uint4 m = *(const uint4*)row;
                    float v1 = bf2f((u16)(m.x & 0xffff)), v2 = bf2f((u16)(m.x >> 16));
                    float v3 = bf2f((u16)(m.y & 0xffff)), v4 = bf2f((u16)(m.y >> 16));
                    float v5 = bf2f((u16)(m.z & 0xffff)), v6 = bf2f((u16)(m.z >> 16));
                    float v7 = bf2f((u16)(m.w & 0xffff)), v8 = bf2f((u16)(m.w >> 16));
                    float v9 = bf2f(row[8]);
                    const float w0 = w9[dy * 3], w1 = w9[dy * 3 + 1], w2 = w9[dy * 3 + 2];
                    acc[0] += w0 * v0 + w1 * v1 + w2 * v2;
                    acc[1] += w0 * v1 + w1 * v2 + w2 * v3;
                    acc[2] += w0 * v2 + w1 * v3 + w2 * v4;
                    acc[3] += w0 * v3 + w1 * v4 + w2 * v5;
                    acc[4] += w0 * v4 + w1 * v5 + w2 * v6;
                    acc[5] += w0 * v5 + w1 * v6 + w2 * v7;
                    acc[6] += w0 * v6 + w1 * v7 + w2 * v8;
                    acc[7] += w0 * v7 + w1 * v8 + w2 * v9;
                }
            }
            bf16x8 a;
#pragma unroll
            for (int c = 0; c < 8; ++c) a[c] = (short)f2bf(acc[c]);
            vfr[kk] = a;
        }
    }
    __syncthreads();   // all A (V) reads done -> A reusable for Q

    // ---- stage Q -> A (loads issue here; stores sink into convK below) ----
#pragma unroll
    for (int i = 0; i < 4; ++i) {
        int idx = i * 512 + t;
        int r = idx >> 4, c16 = idx & 15;
        *(uint4*)(&A[r * 144 + 8 + c16 * 8]) =
            *(const uint4*)(&qkv[qoff + ((size_t)r << 7) + c16 * 8]);
    }

    // ---- K conv -> kfr (reads B only; independent of Q staging) ----
    bf16x8 kfr[4];
    float rkinv;
    {
        float w9[9];
        const float* wp = dww + (size_t)(128 + ch) * 9;
#pragma unroll
        for (int i = 0; i < 9; ++i) w9[i] = wp[i];
        const float gb = dwb[128 + ch];
        float ssq = 0.f;
#pragma unroll
        for (int kk = 0; kk < 4; ++kk) {
            const int c0 = quad * 8 + kk * 32;
            float acc[8];
#pragma unroll
            for (int c = 0; c < 8; ++c) acc[c] = gb;
#pragma unroll
            for (int pr = 0; pr < 3; ++pr) {
                int rr = wr + pr - 1;
                if ((unsigned)rr < 128u) {
                    const u16* row = &Bq[rr * 144 + 8 + c0];
                    float v0 = bf2f(row[-1]);
                    uint4 m = *(const uint4*)row;
                    float v1 = bf2f((u16)(m.x & 0xffff)), v2 = bf2f((u16)(m.x >> 16));
                    float v3 = bf2f((u16)(m.y & 0xffff)), v4 = bf2f((u16)(m.y >> 16));
                    float v5 = bf2f((u16)(m.z & 0xffff)), v6 = bf2f((u16)(m.z >> 16));
                    float v7 = bf2f((u16)(m.w & 0xffff)), v8 = bf2f((u16)(m.w >> 16));
                    float v9 = bf2f(row[8]);
                    const float w0 = w9[pr], w1 = w9[3 + pr], w2 = w9[6 + pr];
                    acc[0] += w0 * v0 + w1 * v1 + w2 * v2;
                    acc[1] += w0 * v1 + w1 * v2 + w2 * v3;
                    acc[2] += w0 * v2 + w1 * v3 + w2 * v4;
                    acc[3] += w0 * v3 + w1 * v4 + w2 * v5;
                    acc[4] += w0 * v4 + w1 * v5 + w2 * v6;
                    acc[5] += w0 * v5 + w1 * v6 + w2 * v7;
                    acc[6] += w0 * v6 + w1 * v7 + w2 * v8;
                    acc[7] += w0 * v7 + w1 * v8 + w2 * v9;
                }
            }
            bf16x8 a;
#pragma unroll
            for (int c = 0; c < 8; ++c) {
                u16 uv = f2bf(acc[c]);
                a[c] = (short)uv;
                float f = bf2f(uv);
                ssq += f * f;
            }
            kfr[kk] = a;
        }
        ssq += __shfl_xor(ssq, 16);
        ssq += __shfl_xor(ssq, 32);
        rkinv = 1.0f / fmaxf(sqrtf(ssq), 1e-12f);
    }
    __syncthreads();   // Q staged into A + all B (K) reads done

    // ---- Q conv (thread-parallel, 4 passes) -> direct swizzled Qt write ----
    const int jr0 = t >> 4, seg = t & 15;
    {
        float w9[9];
        const float* wp = dww + (size_t)ch * 9;
#pragma unroll
        for (int i = 0; i < 9; ++i) w9[i] = wp[i];
        const float gb = dwb[ch];
#pragma unroll
        for (int pass = 0; pass < 4; ++pass) {
            const int j = pass * 32 + jr0;
            float acc[8];
#pragma unroll
            for (int c = 0; c < 8; ++c) acc[c] = gb;
#pragma unroll
            for (int pr = 0; pr < 3; ++pr) {
                int rr = j + pr - 1;
                if ((unsigned)rr < 128u) {
                    const u16* row = &A[rr * 144 + 8 + seg * 8];
                    float v0 = bf2f(row[-1]);
                    uint4 m = *(const uint4*)row;
                    float v1 = bf2f((u16)(m.x & 0xffff)), v2 = bf2f((u16)(m.x >> 16));
                    float v3 = bf2f((u16)(m.y & 0xffff)), v4 = bf2f((u16)(m.y >> 16));
                    float v5 = bf2f((u16)(m.z & 0xffff)), v6 = bf2f((u16)(m.z >> 16));
                    float v7 = bf2f((u16)(m.w & 0xffff)), v8 = bf2f((u16)(m.w >> 16));
                    float v9 = bf2f(row[8]);
                    const float w0 = w9[pr], w1 = w9[3 + pr], w2 = w9[6 + pr];
                    acc[0] += w0 * v0 + w1 * v1 + w2 * v2;
                    acc[1] += w0 * v1 + w1 * v2 + w2 * v3;
                    acc[2] += w0 * v2 + w1 * v3 + w2 * v4;
                    acc[3] += w0 * v3 + w1 * v4 + w2 * v5;
                    acc[4] += w0 * v4 + w1 * v5 + w2 * v6;
                    acc[5] += w0 * v5 + w1 * v6 + w2 * v7;
                    acc[6] += w0 * v6 + w1 * v7 + w2 * v8;
                    acc[7] += w0 * v7 + w1 * v8 + w2 * v9;
                }
            }
            u16 tmp[8];
            float ssq = 0.f;
#pragma unroll
            for (int c = 0; c < 8; ++c) {
                u16 uv = f2bf(acc[c]);
                tmp[c] = uv;
                float f = bf2f(uv);
                ssq += f * f;
            }
            ssq += __shfl_xor(ssq, 1);
            ssq += __shfl_xor(ssq, 2);
            ssq += __shfl_xor(ssq, 4);
            ssq += __shfl_xor(ssq, 8);
            if (seg == 0) rqk[j] = ssq;
            *(uint4*)(&Qt[j * 128 + ((seg ^ (j & 15)) << 3)]) = *(const uint4*)tmp;
        }
    }
    __syncthreads();   // Qt + raw rqk visible; A now dead (Osh reusable)

    if (t < 128) rqk[t] = 1.0f / fmaxf(sqrtf(rqk[t]), 1e-12f);
    __syncthreads();

    // ---- S = K_dw . Q_dw^T via MFMA (B-operand = kfr registers) ----
    f32x4 S[8] = {};
#pragma unroll
    for (int kk = 0; kk < 4; ++kk) {
        const int sw = ((kk * 4 + quad) ^ m16) << 3;
#pragma unroll
        for (int jt = 0; jt < 8; ++jt) {
            bf16x8 af = *(const bf16x8*)(&Qt[(jt * 16 + m16) * 128 + sw]);
            S[jt] = MFMA16(af, kfr[kk], S[jt]);
        }
    }

    // ---- softmax in place in S ----
    const float sc = temp[head] * rkinv;
    float vmax = -1e30f;
#pragma unroll
    for (int jt = 0; jt < 8; ++jt)
#pragma unroll
        for (int r = 0; r < 4; ++r) {
            float v = S[jt][r] * (rqk[jt * 16 + quad * 4 + r] * sc);
            S[jt][r] = v;
            vmax = fmaxf(vmax, v);
        }
    vmax = fmaxf(vmax, __shfl_xor(vmax, 16));
    vmax = fmaxf(vmax, __shfl_xor(vmax, 32));
    float sum = 0.f;
#pragma unroll
    for (int jt = 0; jt < 8; ++jt)
#pragma unroll
        for (int r = 0; r < 4; ++r) {
            float e = __expf(S[jt][r] - vmax);
            S[jt][r] = e;
            sum += e;
        }
    sum += __shfl_xor(sum, 16);
    sum += __shfl_xor(sum, 32);
    const float inv = 1.0f / sum;

    __syncthreads();   // Qt reads done; Pt (alias) writable

    {
        const int k = wr;
        u16* prow = Pt + k * 128;
#pragma unroll
        for (int jt = 0; jt < 8; ++jt)
#pragma unroll
            for (int pr = 0; pr < 2; ++pr) {
                int j0w = jt * 16 + quad * 4 + pr * 2;
                u32 pk = (u32)f2bf(S[jt][pr * 2] * inv) |
                         ((u32)f2bf(S[jt][pr * 2 + 1] * inv) << 16);
                *(u32*)(prow + (((j0w >> 3) ^ (k & 15)) << 3) + (j0w & 7)) = pk;
            }
    }
    __syncthreads();

    f32x4 O[8] = {};
#pragma unroll
    for (int kk = 0; kk < 4; ++kk) {
        const int sw = ((kk * 4 + quad) ^ m16) << 3;
#pragma unroll
        for (int nt = 0; nt < 8; ++nt) {
            bf16x8 bf = *(const bf16x8*)(&Pt[(nt * 16 + m16) * 128 + sw]);
            O[nt] = MFMA16(vfr[kk], bf, O[nt]);
        }
    }
    __syncthreads();   // Pt reads done

#pragma unroll
    for (int nt = 0; nt < 8; ++nt) {
        int k = nt * 16 + m16;
#pragma unroll
        for (int r = 0; r < 4; ++r) {
            int i = wave * 16 + quad * 4 + r;
            Osh[i * 128 + (((k >> 3) ^ (i & 15)) << 3) + (k & 7)] = f2bf(O[nt][r]);
        }
    }
    __syncthreads();

    u16* ob = outp + (((size_t)(b * 128 + ch)) << 14);
#pragma unroll
    for (int it = 0; it < 4; ++it) {
        int idx = it * 512 + t;
        int row = idx >> 4, gk = idx & 15;
        uint4 v = *(const uint4*)(&Osh[row * 128 + ((gk ^ (row & 15)) << 3)]);
        *(uint4*)(&ob[(row << 7) + gk * 8]) = v;
    }
}

// ---------------------------------------------------------------------------
// K4 v3: proj 1x1 conv with STAGED fp32 epilogue.
// ---------------------------------------------------------------------------
__global__ __launch_bounds__(512, 6) void k_proj(const u16* __restrict__ ain,
                                                 const float* __restrict__ w,
                                                 const float* __restrict__ bias,
                                                 float* __restrict__ outp) {
    extern __shared__ char smem[];
    u16* Bt = (u16*)smem;            // 32 KB swizzled [p][g]
    u16* Sg = Bt + 16384;            // [32][144] staging (9 KB)
    float* Cs = (float*)smem;        // [64][132] fp32, aliases Bt+Sg
    const int h = blockIdx.x, b = blockIdx.y;
    const int t = threadIdx.x;

    const int ldr = t >> 4, ldj8 = t & 15;
    const int gig = t >> 7, gp = t & 127;
    const u16* gcol = &Sg[(gig * 8) * 144 + gp];
    u16* gdst = Bt + gp * 128;
#pragma unroll
    for (int ph = 0; ph < 4; ++ph) {
        int ch = ph * 32 + ldr;
        *(uint4*)(&Sg[ldr * 144 + ldj8 * 8]) =
            *(const uint4*)(&ain[(((size_t)(b * 128 + ch)) << 14) + (h << 7) + ldj8 * 8]);
        __syncthreads();
        u16 tmp[8];
#pragma unroll
        for (int c = 0; c < 8; ++c) tmp[c] = gcol[c * 144];
        int g = ph * 4 + gig;
        *(uint4*)(gdst + ((g ^ (gp & 15)) << 3)) = *(const uint4*)tmp;
        __syncthreads();
    }

    const int wave = t >> 6, lane = t & 63, m16 = lane & 15, quad = lane >> 4;
    bf16x8 afr[4];
    {
        const float* wp0 = w + (size_t)(wave * 16 + m16) * 128 + quad * 8;
#pragma unroll
        for (int kk = 0; kk < 4; ++kk) {
            float4 w0 = *(const float4*)(wp0 + kk * 32);
            float4 w1 = *(const float4*)(wp0 + kk * 32 + 4);
            bf16x8 a;
            a[0] = (short)f2bf(w0.x); a[1] = (short)f2bf(w0.y);
            a[2] = (short)f2bf(w0.z); a[3] = (short)f2bf(w0.w);
            a[4] = (short)f2bf(w1.x); a[5] = (short)f2bf(w1.y);
            a[6] = (short)f2bf(w1.z); a[7] = (short)f2bf(w1.w);
            afr[kk] = a;
        }
    }

    f32x4 acc[8] = {};
#pragma unroll
    for (int kk = 0; kk < 4; ++kk) {
        const int g = kk * 4 + quad;
#pragma unroll
        for (int nt = 0; nt < 8; ++nt) {
            int p = nt * 16 + m16;
            bf16x8 bf = *(const bf16x8*)(&Bt[p * 128 + ((g ^ (p & 15)) << 3)]);
            acc[nt] = MFMA16(afr[kk], bf, acc[nt]);
        }
    }

    float bv[4];
#pragma unroll
    for (int r = 0; r < 4; ++r) bv[r] = bias[wave * 16 + quad * 4 + r];
    float* ob = outp + (((size_t)(b * 128)) << 14) + (h << 7);

    __syncthreads();   // all Bt reads done; Cs (alias) writable

    if (wave < 4) {
#pragma unroll
        for (int nt = 0; nt < 8; ++nt) {
            int p = nt * 16 + m16;
#pragma unroll
            for (int r = 0; r < 4; ++r)
                Cs[(wave * 16 + quad * 4 + r) * 132 + p] = acc[nt][r] + bv[r];
        }
    }
    __syncthreads();
#pragma unroll
    for (int it = 0; it < 4; ++it) {
        int idx = it * 512 + t;
        int co = idx >> 5, col = idx & 31;
        *(float4*)(&ob[((size_t)co << 14) + col * 4]) = *(const float4*)(&Cs[co * 132 + col * 4]);
    }
    __syncthreads();

    if (wave >= 4) {
#pragma unroll
        for (int nt = 0; nt < 8; ++nt) {
            int p = nt * 16 + m16;
#pragma unroll
            for (int r = 0; r < 4; ++r)
                Cs[((wave - 4) * 16 + quad * 4 + r) * 132 + p] = acc[nt][r] + bv[r];
        }
    }
    __syncthreads();
    float* ob2 = ob + ((size_t)64 << 14);
#pragma unroll
    for (int it = 0; it < 4; ++it) {
        int idx = it * 512 + t;
        int co = idx >> 5, col = idx & 31;
        *(float4*)(&ob2[((size_t)co << 14) + col * 4]) = *(const float4*)(&Cs[co * 132 + col * 4]);
    }
}

// ---------------------------------------------------------------------------
extern "C" void kernel_launch(void* const* d_in, const int* in_sizes, int n_in,
                              void* d_out, int out_size, void* d_ws, size_t ws_size,
                              hipStream_t stream) {
    const float* x      = (const float*)d_in[0];
    const float* qkv_w  = (const float*)d_in[1];
    const float* qkv_b  = (const float*)d_in[2];
    const float* dw_w   = (const float*)d_in[3];
    const float* dw_b   = (const float*)d_in[4];
    const float* proj_w = (const float*)d_in[5];
    const float* proj_b = (const float*)d_in[6];
    const float* temp   = (const float*)d_in[7];
    float* out = (float*)d_out;

    u16* buf1 = (u16*)d_ws;
    u16* buf2 = buf1 + (size_t)8 * 384 * 16384;

    hipFuncSetAttribute((const void*)k_qkv,  hipFuncAttributeMaxDynamicSharedMemorySize, 32768);
    hipFuncSetAttribute((const void*)k_attn, hipFuncAttributeMaxDynamicSharedMemorySize, 74240);
    hipFuncSetAttribute((const void*)k_proj, hipFuncAttributeMaxDynamicSharedMemorySize, 41984);

    k_xpose<<<dim3(128, 8), 256, 0, stream>>>(x, buf2);
    // q,k planes column-major; v plane row-major (single launch)
    k_qkv<<<dim3(128, 3, 8), 512, 32768, stream>>>(buf2, qkv_w, qkv_b, buf1);
    k_attn<<<dim3(128, 8), 512, 74240, stream>>>(buf1, dw_w, dw_b, temp, buf2);
    k_proj<<<dim3(128, 8), 512, 41984, stream>>>(buf2, proj_w, proj_b, out);
}

// Round 13
// 246.654 us; speedup vs baseline: 1.0069x; 1.0069x over previous
//
#include <hip/hip_runtime.h>

typedef unsigned short u16;
typedef unsigned int   u32;

typedef short bf16x8 __attribute__((ext_vector_type(8)));
typedef float f32x4  __attribute__((ext_vector_type(4)));

__device__ __forceinline__ float bf2f(u16 u) { return __uint_as_float(((u32)u) << 16); }
__device__ __forceinline__ u16 f2bf(float f) {
    u32 u = __float_as_uint(f);
    return (u16)((u + 0x7fffu + ((u >> 16) & 1u)) >> 16);
}

#define MFMA16(a, b, c) __builtin_amdgcn_mfma_f32_16x16x32_bf16(a, b, c, 0, 0, 0)

// ---------------------------------------------------------------------------
// K0: transpose x[b][ci][p] fp32 -> xT[b][p][ci] bf16.
// ---------------------------------------------------------------------------
__global__ __launch_bounds__(256, 4) void k_xpose(const float* __restrict__ x,
                                                  u16* __restrict__ xT) {
    __shared__ u16 Xs[128 * 128];
    const int ptile = blockIdx.x, b = blockIdx.y;
    const int t = threadIdx.x;
    const float* xb = x + (((size_t)b) << 21) + ptile * 128;
#pragma unroll
    for (int i = 0; i < 16; ++i) {
        int idx = i * 256 + t;
        int ci = idx >> 5, pq = idx & 31;
        float4 v = *(const float4*)(xb + (((size_t)ci) << 14) + pq * 4);
        u32 lo = (u32)f2bf(v.x) | ((u32)f2bf(v.y) << 16);
        u32 hi = (u32)f2bf(v.z) | ((u32)f2bf(v.w) << 16);
        uint2 pk; pk.x = lo; pk.y = hi;
        int cq = ci >> 3;
        *(uint2*)(&Xs[ci * 128 + ((pq ^ cq) << 2)]) = pk;
    }
    __syncthreads();
    u16* ob = xT + (((size_t)b) << 21) + ((size_t)(ptile * 128)) * 128;
#pragma unroll
    for (int j = 0; j < 8; ++j) {
        int p = j * 16 + (t >> 4), cq = t & 15;
        u16 tmp[8];
#pragma unroll
        for (int c = 0; c < 8; ++c) {
            int ci = cq * 8 + c;
            tmp[c] = Xs[ci * 128 + (((p >> 2) ^ cq) << 2) + (p & 3)];
        }
        *(uint4*)(&ob[(size_t)p * 128 + cq * 8]) = *(const uint4*)tmp;
    }
}

// ---------------------------------------------------------------------------
// K1 v5: qkv 1x1 conv, single launch; per-cg output layout.
//   cg 0,1 (q,k): plane written column-major  [ch][w][h]
//   cg 2   (v)  : plane written row-major     [ch][h][w]
// ---------------------------------------------------------------------------
__global__ __launch_bounds__(512, 6) void k_qkv(const u16* __restrict__ xT,
                                                const float* __restrict__ w,
                                                const float* __restrict__ bias,
                                                u16* __restrict__ out1) {
    extern __shared__ char smem[];
    u16* Bt = (u16*)smem;            // 32 KB swizzled [p][g]
    u16* Cs = Bt + 2048 * 8;         // [64 co][136 p] = 17 KB
    const int h = blockIdx.x, cg = blockIdx.y, b = blockIdx.z;
    const int t = threadIdx.x;
    const int psh = (cg < 2) ? 14 : 7;       // CM : RM spatial stride shift
    const int hsh = (cg < 2) ? 7 : 14;

    const u16* xb = xT + (((size_t)b) << 21) + (h << hsh);
#pragma unroll
    for (int i = 0; i < 4; ++i) {
        int slot = i * 512 + t;
        int p = slot >> 4, g = slot & 15;
        int gg = g ^ (p & 15);
        uint4 v = *(const uint4*)(&xb[(p << psh) + gg * 8]);
        *(uint4*)(&Bt[slot * 8]) = v;
    }

    const int wave = t >> 6, lane = t & 63, m16 = lane & 15, quad = lane >> 4;
    bf16x8 afr[4];
    {
        const float* wp0 = w + (size_t)(cg * 128 + wave * 16 + m16) * 128 + quad * 8;
#pragma unroll
        for (int kk = 0; kk < 4; ++kk) {
            float4 w0 = *(const float4*)(wp0 + kk * 32);
            float4 w1 = *(const float4*)(wp0 + kk * 32 + 4);
            bf16x8 a;
            a[0] = (short)f2bf(w0.x); a[1] = (short)f2bf(w0.y);
            a[2] = (short)f2bf(w0.z); a[3] = (short)f2bf(w0.w);
            a[4] = (short)f2bf(w1.x); a[5] = (short)f2bf(w1.y);
            a[6] = (short)f2bf(w1.z); a[7] = (short)f2bf(w1.w);
            afr[kk] = a;
        }
    }
    __syncthreads();

    f32x4 acc[8] = {};
#pragma unroll
    for (int kk = 0; kk < 4; ++kk) {
        const int g = kk * 4 + quad;
#pragma unroll
        for (int nt = 0; nt < 8; ++nt) {
            int p = nt * 16 + m16;
            bf16x8 bf = *(const bf16x8*)(&Bt[p * 128 + ((g ^ (p & 15)) << 3)]);
            acc[nt] = MFMA16(afr[kk], bf, acc[nt]);
        }
    }

    float bv[4];
#pragma unroll
    for (int r = 0; r < 4; ++r) bv[r] = bias[cg * 128 + wave * 16 + quad * 4 + r];

    u16* ob = out1 + (((size_t)(b * 384 + cg * 128)) << 14) + (h << 7);

    if (wave < 4) {
#pragma unroll
        for (int nt = 0; nt < 8; ++nt) {
            int p = nt * 16 + m16;
#pragma unroll
            for (int r = 0; r < 4; ++r)
                Cs[(wave * 16 + quad * 4 + r) * 136 + p] = f2bf(acc[nt][r] + bv[r]);
        }
    }
    __syncthreads();
#pragma unroll
    for (int it = 0; it < 2; ++it) {
        int idx = it * 512 + t;
        int co = idx >> 4, cp = idx & 15;
        *(uint4*)(&ob[((size_t)co << 14) + cp * 8]) = *(const uint4*)(&Cs[co * 136 + cp * 8]);
    }
    __syncthreads();

    if (wave >= 4) {
#pragma unroll
        for (int nt = 0; nt < 8; ++nt) {
            int p = nt * 16 + m16;
#pragma unroll
            for (int r = 0; r < 4; ++r)
                Cs[((wave - 4) * 16 + quad * 4 + r) * 136 + p] = f2bf(acc[nt][r] + bv[r]);
        }
    }
    __syncthreads();
    u16* ob2 = ob + ((size_t)64 << 14);
#pragma unroll
    for (int it = 0; it < 2; ++it) {
        int idx = it * 512 + t;
        int co = idx >> 4, cp = idx & 15;
        *(uint4*)(&ob2[((size_t)co << 14) + cp * 8]) = *(const uint4*)(&Cs[co * 136 + cp * 8]);
    }
}

// ---------------------------------------------------------------------------
// K3 v11: fused dw3x3 + attention; dual-buffer + stageQ hidden under convK.
//   LDS: A [128][144] (V raw -> Q raw; Osh aliases)
//        B [128][144] (K raw; Qt/Pt alias)  -> 74.2 KB, 2 blocks/CU, (512,4).
//   Best-measured configuration (65.5 us clean, VGPR 64, no scratch).
// ---------------------------------------------------------------------------
__global__ __launch_bounds__(512, 4) void k_attn(const u16* __restrict__ qkv,
                                                 const float* __restrict__ dww,
                                                 const float* __restrict__ dwb,
                                                 const float* __restrict__ temp,
                                                 u16* __restrict__ outp) {
    extern __shared__ char smem[];
    u16* A  = (u16*)smem;                  // [128][144] raw plane (V, then Q)
    u16* Bq = (u16*)(smem + 36864);        // [128][144] raw K plane
    float* rqk = (float*)(smem + 73728);   // [128] q norms
    u16* Qt  = Bq;                         // swizzled [j][i], over K raw
    u16* Pt  = Bq;
    u16* Osh = A;

    const int ch = blockIdx.x, b = blockIdx.y;
    const int head = ch >> 5;
    const int t = threadIdx.x;
    const size_t qoff = ((size_t)(b * 384 + ch)) << 14;
    const size_t koff = qoff + ((size_t)128 << 14);
    const size_t voff = qoff + ((size_t)256 << 14);

    const int wave = t >> 6, lane = t & 63, m16 = lane & 15, quad = lane >> 4;
    const int wr = wave * 16 + m16;        // this lane's owned row

    // ---- stage V->A and K->B together (+ zero pads for both) ----
#pragma unroll
    for (int i = 0; i < 4; ++i) {
        int idx = i * 512 + t;
        int r = idx >> 4, c16 = idx & 15;
        *(uint4*)(&A[r * 144 + 8 + c16 * 8]) =
            *(const uint4*)(&qkv[voff + ((size_t)r << 7) + c16 * 8]);
        *(uint4*)(&Bq[r * 144 + 8 + c16 * 8]) =
            *(const uint4*)(&qkv[koff + ((size_t)r << 7) + c16 * 8]);
    }
    {
        uint4 z = {0, 0, 0, 0};
        if (t < 256) {
            int r = t >> 1, side = t & 1;
            *(uint4*)(&A[r * 144 + side * 136]) = z;
        } else {
            int u = t - 256;
            int r = u >> 1, side = u & 1;
            *(uint4*)(&Bq[r * 144 + side * 136]) = z;
        }
    }
    __syncthreads();

    // ---- V conv -> vfr (row-major taps; reads A) ----
    bf16x8 vfr[4];
    {
        float w9[9];
        const float* wp = dww + (size_t)(256 + ch) * 9;
#pragma unroll
        for (int i = 0; i < 9; ++i) w9[i] = wp[i];
        const float gb = dwb[256 + ch];
#pragma unroll
        for (int kk = 0; kk < 4; ++kk) {
            const int c0 = quad * 8 + kk * 32;
            float acc[8];
#pragma unroll
            for (int c = 0; c < 8; ++c) acc[c] = gb;
#pragma unroll
            for (int dy = 0; dy < 3; ++dy) {
                int rr = wr + dy - 1;
                if ((unsigned)rr < 128u) {
                    const u16* row = &A[rr * 144 + 8 + c0];
                    float v0 = bf2f(row[-1]);
                    uint4 m = *(const uint4*)row;
                    float v1 = bf2f((u16)(m.x & 0xffff)), v2 = bf2f((u16)(m.x >> 16));
                    float v3 = bf2f((u16)(m.y & 0xffff)), v4 = bf2f((u16)(m.y >> 16));
                    float v5 = bf2f((u16)(m.z & 0xffff)), v6 = bf2f((u16)(m.z >> 16));
                    float v7 = bf2f((u16)(m.w & 0xffff)), v8 = bf2f((u16)(m.w >> 16));
                    float v9 = bf2f(row[8]);
                    const float w0 = w9[dy * 3], w1 = w9[dy * 3 + 1], w2 = w9[dy * 3 + 2];
                    acc[0] += w0 * v0 + w1 * v1 + w2 * v2;
                    acc[1] += w0 * v1 + w1 * v2 + w2 * v3;
                    acc[2] += w0 * v2 + w1 * v3 + w2 * v4;
                    acc[3] += w0 * v3 + w1 * v4 + w2 * v5;
                    acc[4] += w0 * v4 + w1 * v5 + w2 * v6;
                    acc[5] += w0 * v5 + w1 * v6 + w2 * v7;
                    acc[6] += w0 * v6 + w1 * v7 + w2 * v8;
                    acc[7] += w0 * v7 + w1 * v8 + w2 * v9;
                }
            }
            bf16x8 a;
#pragma unroll
            for (int c = 0; c < 8; ++c) a[c] = (short)f2bf(acc[c]);
            vfr[kk] = a;
        }
    }
    __syncthreads();   // all A (V) reads done -> A reusable for Q

    // ---- stage Q -> A (loads issue here; stores sink into convK below) ----
#pragma unroll
    for (int i = 0; i < 4; ++i) {
        int idx = i * 512 + t;
        int r = idx >> 4, c16 = idx & 15;
        *(uint4*)(&A[r * 144 + 8 + c16 * 8]) =
            *(const uint4*)(&qkv[qoff + ((size_t)r << 7) + c16 * 8]);
    }

    // ---- K conv -> kfr (reads B only; independent of Q staging) ----
    bf16x8 kfr[4];
    float rkinv;
    {
        float w9[9];
        const float* wp = dww + (size_t)(128 + ch) * 9;
#pragma unroll
        for (int i = 0; i < 9; ++i) w9[i] = wp[i];
        const float gb = dwb[128 + ch];
        float ssq = 0.f;
#pragma unroll
        for (int kk = 0; kk < 4; ++kk) {
            const int c0 = quad * 8 + kk * 32;
            float acc[8];
#pragma unroll
            for (int c = 0; c < 8; ++c) acc[c] = gb;
#pragma unroll
            for (int pr = 0; pr < 3; ++pr) {
                int rr = wr + pr - 1;
                if ((unsigned)rr < 128u) {
                    const u16* row = &Bq[rr * 144 + 8 + c0];
                    float v0 = bf2f(row[-1]);
                    uint4 m = *(const uint4*)row;
                    float v1 = bf2f((u16)(m.x & 0xffff)), v2 = bf2f((u16)(m.x >> 16));
                    float v3 = bf2f((u16)(m.y & 0xffff)), v4 = bf2f((u16)(m.y >> 16));
                    float v5 = bf2f((u16)(m.z & 0xffff)), v6 = bf2f((u16)(m.z >> 16));
                    float v7 = bf2f((u16)(m.w & 0xffff)), v8 = bf2f((u16)(m.w >> 16));
                    float v9 = bf2f(row[8]);
                    const float w0 = w9[pr], w1 = w9[3 + pr], w2 = w9[6 + pr];
                    acc[0] += w0 * v0 + w1 * v1 + w2 * v2;
                    acc[1] += w0 * v1 + w1 * v2 + w2 * v3;
                    acc[2] += w0 * v2 + w1 * v3 + w2 * v4;
                    acc[3] += w0 * v3 + w1 * v4 + w2 * v5;
                    acc[4] += w0 * v4 + w1 * v5 + w2 * v6;
                    acc[5] += w0 * v5 + w1 * v6 + w2 * v7;
                    acc[6] += w0 * v6 + w1 * v7 + w2 * v8;
                    acc[7] += w0 * v7 + w1 * v8 + w2 * v9;
                }
            }
            bf16x8 a;
#pragma unroll
            for (int c = 0; c < 8; ++c) {
                u16 uv = f2bf(acc[c]);
                a[c] = (short)uv;
                float f = bf2f(uv);
                ssq += f * f;
            }
            kfr[kk] = a;
        }
        ssq += __shfl_xor(ssq, 16);
        ssq += __shfl_xor(ssq, 32);
        rkinv = 1.0f / fmaxf(sqrtf(ssq), 1e-12f);
    }
    __syncthreads();   // Q staged into A + all B (K) reads done

    // ---- Q conv (thread-parallel, 4 passes) -> direct swizzled Qt write ----
    const int jr0 = t >> 4, seg = t & 15;
    {
        float w9[9];
        const float* wp = dww + (size_t)ch * 9;
#pragma unroll
        for (int i = 0; i < 9; ++i) w9[i] = wp[i];
        const float gb = dwb[ch];
#pragma unroll
        for (int pass = 0; pass < 4; ++pass) {
            const int j = pass * 32 + jr0;
            float acc[8];
#pragma unroll
            for (int c = 0; c < 8; ++c) acc[c] = gb;
#pragma unroll
            for (int pr = 0; pr < 3; ++pr) {
                int rr = j + pr - 1;
                if ((unsigned)rr < 128u) {
                    const u16* row = &A[rr * 144 + 8 + seg * 8];
                    float v0 = bf2f(row[-1]);
                    uint4 m = *(const uint4*)row;
                    float v1 = bf2f((u16)(m.x & 0xffff)), v2 = bf2f((u16)(m.x >> 16));
                    float v3 = bf2f((u16)(m.y & 0xffff)), v4 = bf2f((u16)(m.y >> 16));
                    float v5 = bf2f((u16)(m.z & 0xffff)), v6 = bf2f((u16)(m.z >> 16));
                    float v7 = bf2f((u16)(m.w & 0xffff)), v8 = bf2f((u16)(m.w >> 16));
                    float v9 = bf2f(row[8]);
                    const float w0 = w9[pr], w1 = w9[3 + pr], w2 = w9[6 + pr];
                    acc[0] += w0 * v0 + w1 * v1 + w2 * v2;
                    acc[1] += w0 * v1 + w1 * v2 + w2 * v3;
                    acc[2] += w0 * v2 + w1 * v3 + w2 * v4;
                    acc[3] += w0 * v3 + w1 * v4 + w2 * v5;
                    acc[4] += w0 * v4 + w1 * v5 + w2 * v6;
                    acc[5] += w0 * v5 + w1 * v6 + w2 * v7;
                    acc[6] += w0 * v6 + w1 * v7 + w2 * v8;
                    acc[7] += w0 * v7 + w1 * v8 + w2 * v9;
                }
            }
            u16 tmp[8];
            float ssq = 0.f;
#pragma unroll
            for (int c = 0; c < 8; ++c) {
                u16 uv = f2bf(acc[c]);
                tmp[c] = uv;
                float f = bf2f(uv);
                ssq += f * f;
            }
            ssq += __shfl_xor(ssq, 1);
            ssq += __shfl_xor(ssq, 2);
            ssq += __shfl_xor(ssq, 4);
            ssq += __shfl_xor(ssq, 8);
            if (seg == 0) rqk[j] = ssq;
            *(uint4*)(&Qt[j * 128 + ((seg ^ (j & 15)) << 3)]) = *(const uint4*)tmp;
        }
    }
    __syncthreads();   // Qt + raw rqk visible; A now dead (Osh reusable)

    if (t < 128) rqk[t] = 1.0f / fmaxf(sqrtf(rqk[t]), 1e-12f);
    __syncthreads();

    // ---- S = K_dw . Q_dw^T via MFMA (B-operand = kfr registers) ----
    f32x4 S[8] = {};
#pragma unroll
    for (int kk = 0; kk < 4; ++kk) {
        const int sw = ((kk * 4 + quad) ^ m16) << 3;
#pragma unroll
        for (int jt = 0; jt < 8; ++jt) {
            bf16x8 af = *(const bf16x8*)(&Qt[(jt * 16 + m16) * 128 + sw]);
            S[jt] = MFMA16(af, kfr[kk], S[jt]);
        }
    }

    // ---- softmax in place in S ----
    const float sc = temp[head] * rkinv;
    float vmax = -1e30f;
#pragma unroll
    for (int jt = 0; jt < 8; ++jt)
#pragma unroll
        for (int r = 0; r < 4; ++r) {
            float v = S[jt][r] * (rqk[jt * 16 + quad * 4 + r] * sc);
            S[jt][r] = v;
            vmax = fmaxf(vmax, v);
        }
    vmax = fmaxf(vmax, __shfl_xor(vmax, 16));
    vmax = fmaxf(vmax, __shfl_xor(vmax, 32));
    float sum = 0.f;
#pragma unroll
    for (int jt = 0; jt < 8; ++jt)
#pragma unroll
        for (int r = 0; r < 4; ++r) {
            float e = __expf(S[jt][r] - vmax);
            S[jt][r] = e;
            sum += e;
        }
    sum += __shfl_xor(sum, 16);
    sum += __shfl_xor(sum, 32);
    const float inv = 1.0f / sum;

    __syncthreads();   // Qt reads done; Pt (alias) writable

    {
        const int k = wr;
        u16* prow = Pt + k * 128;
#pragma unroll
        for (int jt = 0; jt < 8; ++jt)
#pragma unroll
            for (int pr = 0; pr < 2; ++pr) {
                int j0w = jt * 16 + quad * 4 + pr * 2;
                u32 pk = (u32)f2bf(S[jt][pr * 2] * inv) |
                         ((u32)f2bf(S[jt][pr * 2 + 1] * inv) << 16);
                *(u32*)(prow + (((j0w >> 3) ^ (k & 15)) << 3) + (j0w & 7)) = pk;
            }
    }
    __syncthreads();

    f32x4 O[8] = {};
#pragma unroll
    for (int kk = 0; kk < 4; ++kk) {
        const int sw = ((kk * 4 + quad) ^ m16) << 3;
#pragma unroll
        for (int nt = 0; nt < 8; ++nt) {
            bf16x8 bf = *(const bf16x8*)(&Pt[(nt * 16 + m16) * 128 + sw]);
            O[nt] = MFMA16(vfr[kk], bf, O[nt]);
        }
    }
    __syncthreads();   // Pt reads done

#pragma unroll
    for (int nt = 0; nt < 8; ++nt) {
        int k = nt * 16 + m16;
#pragma unroll
        for (int r = 0; r < 4; ++r) {
            int i = wave * 16 + quad * 4 + r;
            Osh[i * 128 + (((k >> 3) ^ (i & 15)) << 3) + (k & 7)] = f2bf(O[nt][r]);
        }
    }
    __syncthreads();

    u16* ob = outp + (((size_t)(b * 128 + ch)) << 14);
#pragma unroll
    for (int it = 0; it < 4; ++it) {
        int idx = it * 512 + t;
        int row = idx >> 4, gk = idx & 15;
        uint4 v = *(const uint4*)(&Osh[row * 128 + ((gk ^ (row & 15)) << 3)]);
        *(uint4*)(&ob[(row << 7) + gk * 8]) = v;
    }
}

// ---------------------------------------------------------------------------
// K4 v3: proj 1x1 conv with STAGED fp32 epilogue.
// ---------------------------------------------------------------------------
__global__ __launch_bounds__(512, 6) void k_proj(const u16* __restrict__ ain,
                                                 const float* __restrict__ w,
                                                 const float* __restrict__ bias,
                                                 float* __restrict__ outp) {
    extern __shared__ char smem[];
    u16* Bt = (u16*)smem;            // 32 KB swizzled [p][g]
    u16* Sg = Bt + 16384;            // [32][144] staging (9 KB)
    float* Cs = (float*)smem;        // [64][132] fp32, aliases Bt+Sg
    const int h = blockIdx.x, b = blockIdx.y;
    const int t = threadIdx.x;

    const int ldr = t >> 4, ldj8 = t & 15;
    const int gig = t >> 7, gp = t & 127;
    const u16* gcol = &Sg[(gig * 8) * 144 + gp];
    u16* gdst = Bt + gp * 128;
#pragma unroll
    for (int ph = 0; ph < 4; ++ph) {
        int ch = ph * 32 + ldr;
        *(uint4*)(&Sg[ldr * 144 + ldj8 * 8]) =
            *(const uint4*)(&ain[(((size_t)(b * 128 + ch)) << 14) + (h << 7) + ldj8 * 8]);
        __syncthreads();
        u16 tmp[8];
#pragma unroll
        for (int c = 0; c < 8; ++c) tmp[c] = gcol[c * 144];
        int g = ph * 4 + gig;
        *(uint4*)(gdst + ((g ^ (gp & 15)) << 3)) = *(const uint4*)tmp;
        __syncthreads();
    }

    const int wave = t >> 6, lane = t & 63, m16 = lane & 15, quad = lane >> 4;
    bf16x8 afr[4];
    {
        const float* wp0 = w + (size_t)(wave * 16 + m16) * 128 + quad * 8;
#pragma unroll
        for (int kk = 0; kk < 4; ++kk) {
            float4 w0 = *(const float4*)(wp0 + kk * 32);
            float4 w1 = *(const float4*)(wp0 + kk * 32 + 4);
            bf16x8 a;
            a[0] = (short)f2bf(w0.x); a[1] = (short)f2bf(w0.y);
            a[2] = (short)f2bf(w0.z); a[3] = (short)f2bf(w0.w);
            a[4] = (short)f2bf(w1.x); a[5] = (short)f2bf(w1.y);
            a[6] = (short)f2bf(w1.z); a[7] = (short)f2bf(w1.w);
            afr[kk] = a;
        }
    }

    f32x4 acc[8] = {};
#pragma unroll
    for (int kk = 0; kk < 4; ++kk) {
        const int g = kk * 4 + quad;
#pragma unroll
        for (int nt = 0; nt < 8; ++nt) {
            int p = nt * 16 + m16;
            bf16x8 bf = *(const bf16x8*)(&Bt[p * 128 + ((g ^ (p & 15)) << 3)]);
            acc[nt] = MFMA16(afr[kk], bf, acc[nt]);
        }
    }

    float bv[4];
#pragma unroll
    for (int r = 0; r < 4; ++r) bv[r] = bias[wave * 16 + quad * 4 + r];
    float* ob = outp + (((size_t)(b * 128)) << 14) + (h << 7);

    __syncthreads();   // all Bt reads done; Cs (alias) writable

    if (wave < 4) {
#pragma unroll
        for (int nt = 0; nt < 8; ++nt) {
            int p = nt * 16 + m16;
#pragma unroll
            for (int r = 0; r < 4; ++r)
                Cs[(wave * 16 + quad * 4 + r) * 132 + p] = acc[nt][r] + bv[r];
        }
    }
    __syncthreads();
#pragma unroll
    for (int it = 0; it < 4; ++it) {
        int idx = it * 512 + t;
        int co = idx >> 5, col = idx & 31;
        *(float4*)(&ob[((size_t)co << 14) + col * 4]) = *(const float4*)(&Cs[co * 132 + col * 4]);
    }
    __syncthreads();

    if (wave >= 4) {
#pragma unroll
        for (int nt = 0; nt < 8; ++nt) {
            int p = nt * 16 + m16;
#pragma unroll
            for (int r = 0; r < 4; ++r)
                Cs[((wave - 4) * 16 + quad * 4 + r) * 132 + p] = acc[nt][r] + bv[r];
        }
    }
    __syncthreads();
    float* ob2 = ob + ((size_t)64 << 14);
#pragma unroll
    for (int it = 0; it < 4; ++it) {
        int idx = it * 512 + t;
        int co = idx >> 5, col = idx & 31;
        *(float4*)(&ob2[((size_t)co << 14) + col * 4]) = *(const float4*)(&Cs[co * 132 + col * 4]);
    }
}

// ---------------------------------------------------------------------------
extern "C" void kernel_launch(void* const* d_in, const int* in_sizes, int n_in,
                              void* d_out, int out_size, void* d_ws, size_t ws_size,
                              hipStream_t stream) {
    const float* x      = (const float*)d_in[0];
    const float* qkv_w  = (const float*)d_in[1];
    const float* qkv_b  = (const float*)d_in[2];
    const float* dw_w   = (const float*)d_in[3];
    const float* dw_b   = (const float*)d_in[4];
    const float* proj_w = (const float*)d_in[5];
    const float* proj_b = (const float*)d_in[6];
    const float* temp   = (const float*)d_in[7];
    float* out = (float*)d_out;

    u16* buf1 = (u16*)d_ws;
    u16* buf2 = buf1 + (size_t)8 * 384 * 16384;

    hipFuncSetAttribute((const void*)k_qkv,  hipFuncAttributeMaxDynamicSharedMemorySize, 50176);
    hipFuncSetAttribute((const void*)k_attn, hipFuncAttributeMaxDynamicSharedMemorySize, 74240);
    hipFuncSetAttribute((const void*)k_proj, hipFuncAttributeMaxDynamicSharedMemorySize, 41984);

    k_xpose<<<dim3(128, 8), 256, 0, stream>>>(x, buf2);
    // q,k planes column-major; v plane row-major (single launch)
    k_qkv<<<dim3(128, 3, 8), 512, 50176, stream>>>(buf2, qkv_w, qkv_b, buf1);
    k_attn<<<dim3(128, 8), 512, 74240, stream>>>(buf1, dw_w, dw_b, temp, buf2);
    k_proj<<<dim3(128, 8), 512, 41984, stream>>>(buf2, proj_w, proj_b, out);
}